// Round 1
// baseline (20189.247 us; speedup 1.0000x reference)
//
#include <hip/hip_runtime.h>
#include <hip/hip_bf16.h>
#include <hip/hip_fp16.h>

#define SS 512
#define BB 64
#define EE 512
#define HH 1024

typedef _Float16 f16x8 __attribute__((ext_vector_type(8)));
typedef float f32x4 __attribute__((ext_vector_type(4)));

__device__ __forceinline__ f16x8 ldh8(const _Float16* p) {
    return *reinterpret_cast<const f16x8*>(p);
}

// ---------- prep: combined [K1+K2][HH] fp32 weights -> transposed [HH][K1+K2] fp16 ----------
__global__ void prep_wt(const float* __restrict__ wih, const float* __restrict__ whh,
                        int K1, int K2, _Float16* __restrict__ out)
{
    int n = blockIdx.x;            // output row = original column
    int K = K1 + K2;
    for (int k = threadIdx.x; k < K; k += blockDim.x) {
        float v = (k < K1) ? wih[(size_t)k * HH + n]
                           : whh[(size_t)(k - K1) * HH + n];
        out[(size_t)n * K + k] = (_Float16)v;
    }
}

// bias layout: [0]=L0 fwd, [1024]=L1 fwd, [2048]=L0 bwd, [3072]=L1 bwd (bih+bhh combined)
__global__ void prep_bias(const float* f0ih, const float* f0hh,
                          const float* f1ih, const float* f1hh,
                          const float* b0ih, const float* b0hh,
                          const float* b1ih, const float* b1hh,
                          float* __restrict__ bias)
{
    int i = threadIdx.x;
    bias[i]          = f0ih[i] + f0hh[i];
    bias[1024 + i]   = f1ih[i] + f1hh[i];
    bias[2048 + i]   = b0ih[i] + b0hh[i];
    bias[3072 + i]   = b1ih[i] + b1hh[i];
}

// ---------- one pipelined super-step ----------
// task 0: layer0 fwd (t), task 1: layer0 bwd (t), task 2: layer1 fwd (t-1), task 3: layer1 bwd (t-1)
// Each task has 16 N-tiles of 64 cols; WG = 4 waves; wave owns [64 rows, 16 cols].
__global__ __launch_bounds__(256)
void step_kernel(const int* __restrict__ x, const float* __restrict__ emb,
                 const _Float16* __restrict__ W0f, const _Float16* __restrict__ W1f,
                 const _Float16* __restrict__ W0b, const _Float16* __restrict__ W1b,
                 const float* __restrict__ bias,
                 _Float16* __restrict__ h0f, _Float16* __restrict__ h1f,
                 _Float16* __restrict__ h0b, _Float16* __restrict__ h1b,
                 float* __restrict__ h1fin,
                 int t)
{
    const int wg   = blockIdx.x;
    const int task = wg >> 4;
    const int tile = wg & 15;
    const int lane = threadIdx.x & 63;
    const int wave = threadIdx.x >> 6;
    const int r    = lane & 15;       // A row within 16-frag / B (output) column within 16
    const int kg   = lane >> 4;       // k-group (8 elements each)
    const int n    = tile * 64 + wave * 16 + r;   // output column

    f32x4 acc[4];
#pragma unroll
    for (int m = 0; m < 4; ++m) acc[m] = (f32x4){0.f, 0.f, 0.f, 0.f};

    if (task < 2) {
        // ---------------- layer 0, time t ----------------
        if (t >= SS) return;
        const int dir   = task;
        const int t_eff = dir ? (SS - 1 - t) : t;
        const _Float16* W = dir ? W0b : W0f;          // [HH][1536]
        _Float16* hbuf    = dir ? h0b : h0f;          // ping-pong [2][64][1024]
        const _Float16* Wrow = W + (size_t)n * 1536;

        // segment 0: embedding (fp32 gathered on the fly), K = 0..511
        const float* arow[4];
#pragma unroll
        for (int m = 0; m < 4; ++m) {
            int b = m * 16 + r;
            arow[m] = emb + (size_t)x[b * SS + t_eff] * EE;
        }
        for (int k0 = 0; k0 < EE; k0 += 32) {
            f16x8 bf = ldh8(Wrow + k0 + kg * 8);
#pragma unroll
            for (int m = 0; m < 4; ++m) {
                const float* p = arow[m] + k0 + kg * 8;
                float4 lo = *reinterpret_cast<const float4*>(p);
                float4 hi = *reinterpret_cast<const float4*>(p + 4);
                f16x8 a;
                a[0] = (_Float16)lo.x; a[1] = (_Float16)lo.y;
                a[2] = (_Float16)lo.z; a[3] = (_Float16)lo.w;
                a[4] = (_Float16)hi.x; a[5] = (_Float16)hi.y;
                a[6] = (_Float16)hi.z; a[7] = (_Float16)hi.w;
                acc[m] = __builtin_amdgcn_mfma_f32_16x16x32_f16(a, bf, acc[m], 0, 0, 0);
            }
        }
        // segment 1: h0(t-1), K = 512..1535  (skipped at t==0: initial state is zero)
        if (t > 0) {
            const _Float16* hprev = hbuf + ((t - 1) & 1) * (BB * HH);
            for (int k0 = 0; k0 < HH; k0 += 32) {
                f16x8 bf = ldh8(Wrow + EE + k0 + kg * 8);
#pragma unroll
                for (int m = 0; m < 4; ++m) {
                    f16x8 a = ldh8(hprev + (m * 16 + r) * HH + k0 + kg * 8);
                    acc[m] = __builtin_amdgcn_mfma_f32_16x16x32_f16(a, bf, acc[m], 0, 0, 0);
                }
            }
        }
        // epilogue: bias + tanh -> fp16 h0(t)
        const float bv = bias[(dir ? 2048 : 0) + n];
        _Float16* hout = hbuf + (t & 1) * (BB * HH);
#pragma unroll
        for (int m = 0; m < 4; ++m)
#pragma unroll
            for (int rr = 0; rr < 4; ++rr) {
                int row = m * 16 + kg * 4 + rr;
                float v = tanhf(acc[m][rr] + bv);
                hout[row * HH + n] = (_Float16)v;
            }
    } else {
        // ---------------- layer 1, time t-1 ----------------
        if (t == 0) return;
        const int tt  = t - 1;
        const int dir = task - 2;
        const _Float16* W  = dir ? W1b : W1f;         // [HH][2048]
        const _Float16* h0buf = dir ? h0b : h0f;
        _Float16* h1buf       = dir ? h1b : h1f;
        const _Float16* Wrow = W + (size_t)n * 2048;

        // segment 0: h0(tt), K = 0..1023
        const _Float16* h0cur = h0buf + (tt & 1) * (BB * HH);
        for (int k0 = 0; k0 < HH; k0 += 32) {
            f16x8 bf = ldh8(Wrow + k0 + kg * 8);
#pragma unroll
            for (int m = 0; m < 4; ++m) {
                f16x8 a = ldh8(h0cur + (m * 16 + r) * HH + k0 + kg * 8);
                acc[m] = __builtin_amdgcn_mfma_f32_16x16x32_f16(a, bf, acc[m], 0, 0, 0);
            }
        }
        // segment 1: h1(tt-1), K = 1024..2047 (skipped at tt==0)
        if (tt > 0) {
            const _Float16* h1prev = h1buf + ((tt - 1) & 1) * (BB * HH);
            for (int k0 = 0; k0 < HH; k0 += 32) {
                f16x8 bf = ldh8(Wrow + HH + k0 + kg * 8);
#pragma unroll
                for (int m = 0; m < 4; ++m) {
                    f16x8 a = ldh8(h1prev + (m * 16 + r) * HH + k0 + kg * 8);
                    acc[m] = __builtin_amdgcn_mfma_f32_16x16x32_f16(a, bf, acc[m], 0, 0, 0);
                }
            }
        }
        const float bv = bias[1024 + (dir ? 2048 : 0) + n];
        _Float16* hout = h1buf + (tt & 1) * (BB * HH);
        float* fout = (tt == SS - 1) ? (h1fin + dir * (BB * HH)) : nullptr;
#pragma unroll
        for (int m = 0; m < 4; ++m)
#pragma unroll
            for (int rr = 0; rr < 4; ++rr) {
                int row = m * 16 + kg * 4 + rr;
                float v = tanhf(acc[m][rr] + bv);
                hout[row * HH + n] = (_Float16)v;
                if (fout) fout[row * HH + n] = v;
            }
    }
}

// ---------- FC head (all fp32) ----------
__global__ void fc1_kernel(const float* __restrict__ h1fin, const float* __restrict__ w,
                           const float* __restrict__ b, float* __restrict__ v)
{
    int idx = blockIdx.x * 256 + threadIdx.x;   // 0..4095 : (batch, out-feature)
    int bb = idx >> 6, nn = idx & 63;
    const float* hf = h1fin + bb * HH;
    const float* hb = h1fin + BB * HH + bb * HH;
    float s = b[nn];
#pragma unroll 8
    for (int k = 0; k < HH; ++k) s += hf[k] * w[k * 64 + nn];
#pragma unroll 8
    for (int k = 0; k < HH; ++k) s += hb[k] * w[(HH + k) * 64 + nn];
    v[idx] = s;
}

__global__ void fc2_kernel(const float* __restrict__ v, const float* __restrict__ w,
                           const float* __restrict__ b, float* __restrict__ out)
{
    int idx = threadIdx.x;
    if (idx >= BB * 2) return;
    int bb = idx >> 1, c = idx & 1;
    float s = b[c];
    const float* vb = v + bb * 64;
#pragma unroll
    for (int j = 0; j < 64; ++j) s += vb[j] * w[j * 2 + c];
    out[bb * 2 + c] = s;
}

extern "C" void kernel_launch(void* const* d_in, const int* in_sizes, int n_in,
                              void* d_out, int out_size, void* d_ws, size_t ws_size,
                              hipStream_t stream)
{
    const int*   x        = (const int*)  d_in[0];
    const float* emb      = (const float*)d_in[1];
    const float* fw0_wih  = (const float*)d_in[2];
    const float* fw0_bih  = (const float*)d_in[3];
    const float* fw0_whh  = (const float*)d_in[4];
    const float* fw0_bhh  = (const float*)d_in[5];
    const float* fw1_wih  = (const float*)d_in[6];
    const float* fw1_bih  = (const float*)d_in[7];
    const float* fw1_whh  = (const float*)d_in[8];
    const float* fw1_bhh  = (const float*)d_in[9];
    const float* bw0_wih  = (const float*)d_in[10];
    const float* bw0_bih  = (const float*)d_in[11];
    const float* bw0_whh  = (const float*)d_in[12];
    const float* bw0_bhh  = (const float*)d_in[13];
    const float* bw1_wih  = (const float*)d_in[14];
    const float* bw1_bih  = (const float*)d_in[15];
    const float* bw1_whh  = (const float*)d_in[16];
    const float* bw1_bhh  = (const float*)d_in[17];
    const float* fc1_w    = (const float*)d_in[18];
    const float* fc1_b    = (const float*)d_in[19];
    const float* fc2_w    = (const float*)d_in[20];
    const float* fc2_b    = (const float*)d_in[21];

    size_t off = 0;
    char* wsb = (char*)d_ws;
    auto take = [&](size_t bytes) -> void* {
        void* p = wsb + off;
        off += (bytes + 255) & ~(size_t)255;
        return p;
    };
    _Float16* W0f   = (_Float16*)take((size_t)HH * 1536 * 2);
    _Float16* W1f   = (_Float16*)take((size_t)HH * 2048 * 2);
    _Float16* W0b   = (_Float16*)take((size_t)HH * 1536 * 2);
    _Float16* W1b   = (_Float16*)take((size_t)HH * 2048 * 2);
    float*    bias  = (float*)   take(4096 * 4);
    _Float16* h0f   = (_Float16*)take((size_t)2 * BB * HH * 2);
    _Float16* h1f   = (_Float16*)take((size_t)2 * BB * HH * 2);
    _Float16* h0b   = (_Float16*)take((size_t)2 * BB * HH * 2);
    _Float16* h1b   = (_Float16*)take((size_t)2 * BB * HH * 2);
    float*    h1fin = (float*)   take((size_t)2 * BB * HH * 4);
    float*    vmid  = (float*)   take(4096 * 4);

    prep_wt<<<HH, 256, 0, stream>>>(fw0_wih, fw0_whh, EE, HH, W0f);
    prep_wt<<<HH, 256, 0, stream>>>(fw1_wih, fw1_whh, HH, HH, W1f);
    prep_wt<<<HH, 256, 0, stream>>>(bw0_wih, bw0_whh, EE, HH, W0b);
    prep_wt<<<HH, 256, 0, stream>>>(bw1_wih, bw1_whh, HH, HH, W1b);
    prep_bias<<<1, 1024, 0, stream>>>(fw0_bih, fw0_bhh, fw1_bih, fw1_bhh,
                                      bw0_bih, bw0_bhh, bw1_bih, bw1_bhh, bias);

    for (int t = 0; t <= SS; ++t) {
        step_kernel<<<64, 256, 0, stream>>>(x, emb, W0f, W1f, W0b, W1b, bias,
                                            h0f, h1f, h0b, h1b, h1fin, t);
    }

    fc1_kernel<<<16, 256, 0, stream>>>(h1fin, fc1_w, fc1_b, vmid);
    fc2_kernel<<<1, 128, 0, stream>>>(vmid, fc2_w, fc2_b, (float*)d_out);
}

// Round 2
// 17139.850 us; speedup vs baseline: 1.1779x; 1.1779x over previous
//
#include <hip/hip_runtime.h>
#include <hip/hip_bf16.h>
#include <hip/hip_fp16.h>

#define SS 512
#define BB 64
#define EE 512
#define HH 1024

typedef _Float16 f16x8 __attribute__((ext_vector_type(8)));
typedef _Float16 f16x4 __attribute__((ext_vector_type(4)));
typedef float f32x4 __attribute__((ext_vector_type(4)));

__device__ __forceinline__ f16x8 ldh8(const _Float16* p) {
    return *reinterpret_cast<const f16x8*>(p);
}

// ---------- prep: combined [K1+K2][HH] fp32 weights -> transposed [HH][K1+K2] fp16 ----------
__global__ void prep_wt(const float* __restrict__ wih, const float* __restrict__ whh,
                        int K1, int K2, _Float16* __restrict__ out)
{
    int n = blockIdx.x;            // output row = original column
    int K = K1 + K2;
    for (int k = threadIdx.x; k < K; k += blockDim.x) {
        float v = (k < K1) ? wih[(size_t)k * HH + n]
                           : whh[(size_t)(k - K1) * HH + n];
        out[(size_t)n * K + k] = (_Float16)v;
    }
}

// bias layout: [0]=L0 fwd, [1024]=L1 fwd, [2048]=L0 bwd, [3072]=L1 bwd (bih+bhh combined)
__global__ void prep_bias(const float* f0ih, const float* f0hh,
                          const float* f1ih, const float* f1hh,
                          const float* b0ih, const float* b0hh,
                          const float* b1ih, const float* b1hh,
                          float* __restrict__ bias)
{
    int i = threadIdx.x;
    bias[i]          = f0ih[i] + f0hh[i];
    bias[1024 + i]   = f1ih[i] + f1hh[i];
    bias[2048 + i]   = b0ih[i] + b0hh[i];
    bias[3072 + i]   = b1ih[i] + b1hh[i];
}

// ---------- embedding pre-gather: embx[t][b][e] = fp16(emb[x[b][t]][e]) ----------
__global__ void prep_embx(const int* __restrict__ x, const float* __restrict__ emb,
                          _Float16* __restrict__ embx)
{
    int t = blockIdx.x >> 6, b = blockIdx.x & 63;
    const float* src = emb + (size_t)x[b * SS + t] * EE;
    _Float16* dst = embx + ((size_t)t * BB + b) * EE;
    int i = threadIdx.x * 4;            // 128 threads * 4 = 512
    float4 v = *reinterpret_cast<const float4*>(src + i);
    f16x4 h;
    h[0] = (_Float16)v.x; h[1] = (_Float16)v.y;
    h[2] = (_Float16)v.z; h[3] = (_Float16)v.w;
    *reinterpret_cast<f16x4*>(dst + i) = h;
}

// ---------- grid barrier: one dedicated counter per super-step (no reset races) ----------
__device__ __forceinline__ void gridbar(unsigned* ctr, unsigned nb)
{
    __syncthreads();
    if (threadIdx.x == 0) {
        __threadfence();                                   // publish my block's stores
        atomicAdd(ctr, 1u);                                // device-scope by default
        while (__hip_atomic_load(ctr, __ATOMIC_RELAXED, __HIP_MEMORY_SCOPE_AGENT) < nb)
            __builtin_amdgcn_s_sleep(2);
        __threadfence();                                   // acquire
    }
    __syncthreads();
}

// ---------- persistent RNN kernel ----------
// 256 blocks (1/CU), 4 tasks x 64 tiles of 16 output cols.
// task 0: L0 fwd(t), 1: L0 bwd(t), 2: L1 fwd(t-1), 3: L1 bwd(t-1)  [software pipeline]
// Weights live in LDS for the whole run; 4 waves split K; LDS cross-wave reduce.
__global__ __launch_bounds__(256, 1)
void rnn_persistent(const int* __restrict__ x, const float* __restrict__ emb,
                    const _Float16* __restrict__ embx,          // may be null -> gather in-loop
                    const _Float16* __restrict__ W0f, const _Float16* __restrict__ W1f,
                    const _Float16* __restrict__ W0b, const _Float16* __restrict__ W1b,
                    const float* __restrict__ bias,
                    _Float16* __restrict__ h0f, _Float16* __restrict__ h1f,
                    _Float16* __restrict__ h0b, _Float16* __restrict__ h1b,
                    float* __restrict__ h1fin, unsigned* __restrict__ ctr)
{
    const int bid  = blockIdx.x;
    const int task = bid >> 6;
    const int tile = bid & 63;
    const int dir  = task & 1;
    const bool isL1 = task >= 2;
    const int lane = threadIdx.x & 63;
    const int wave = threadIdx.x >> 6;
    const int r    = lane & 15;       // output col within tile / A row within 16-frag
    const int kg   = lane >> 4;       // k-group (8 halves)
    const int tid  = threadIdx.x;

    const int K  = isL1 ? 2048 : 1536;
    const int Kp = K + 8;             // LDS row stride (halves): breaks bank aliasing

    __shared__ _Float16 Wlds[16 * 2056];      // 65,792 B (worst case K=2048)
    __shared__ float red[4][64][16];          // 16,384 B

    // --- stage this block's weight slice into LDS (once) ---
    {
        const _Float16* Wg = isL1 ? (dir ? W1b : W1f) : (dir ? W0b : W0f);
        int rowlen = K >> 3;
        for (int idx = tid; idx < 16 * rowlen; idx += 256) {
            int row = idx / rowlen, kk = (idx - row * rowlen) * 8;
            f16x8 v = ldh8(Wg + (size_t)(tile * 16 + row) * K + kk);
            *reinterpret_cast<f16x8*>(&Wlds[row * Kp + kk]) = v;
        }
    }
    __syncthreads();

    _Float16* hbuf0 = dir ? h0b : h0f;        // layer0 state ping-pong [2][64][1024]
    _Float16* h1buf = dir ? h1b : h1f;

    const int nchunk = (K >> 5) >> 2;          // chunks of 32 per wave: 12 (L0) / 16 (L1)
    const int kbase  = wave * nchunk * 32;

    for (int t = 0; t <= SS; ++t) {
        const bool active = isL1 ? (t > 0) : (t < SS);
        if (active) {
            const int tt = isL1 ? (t - 1) : t;
            f32x4 acc[4];
#pragma unroll
            for (int m = 0; m < 4; ++m) acc[m] = (f32x4){0.f, 0.f, 0.f, 0.f};

            if (!isL1) {
                // ---------- layer 0, step tt:  A = [embx(t_eff) | h0(tt-1)] ----------
                const int t_eff = dir ? (SS - 1 - tt) : tt;
                const _Float16* hprev = (tt > 0) ? hbuf0 + ((tt - 1) & 1) * (BB * HH) : nullptr;
                const _Float16* Aemb  = embx ? embx + (size_t)t_eff * (BB * EE) : nullptr;
                const float* erow[4];
                if (!Aemb) {
#pragma unroll
                    for (int m = 0; m < 4; ++m)
                        erow[m] = emb + (size_t)x[(m * 16 + r) * SS + t_eff] * EE;
                }
                for (int i = 0; i < nchunk; ++i) {
                    const int k = kbase + i * 32;
                    f16x8 bf = *reinterpret_cast<const f16x8*>(&Wlds[r * Kp + k + kg * 8]);
                    if (k < EE) {
                        if (Aemb) {
#pragma unroll
                            for (int m = 0; m < 4; ++m) {
                                f16x8 a = ldh8(Aemb + (m * 16 + r) * EE + k + kg * 8);
                                acc[m] = __builtin_amdgcn_mfma_f32_16x16x32_f16(a, bf, acc[m], 0, 0, 0);
                            }
                        } else {
#pragma unroll
                            for (int m = 0; m < 4; ++m) {
                                const float* p = erow[m] + k + kg * 8;
                                float4 lo = *reinterpret_cast<const float4*>(p);
                                float4 hi = *reinterpret_cast<const float4*>(p + 4);
                                f16x8 a;
                                a[0] = (_Float16)lo.x; a[1] = (_Float16)lo.y;
                                a[2] = (_Float16)lo.z; a[3] = (_Float16)lo.w;
                                a[4] = (_Float16)hi.x; a[5] = (_Float16)hi.y;
                                a[6] = (_Float16)hi.z; a[7] = (_Float16)hi.w;
                                acc[m] = __builtin_amdgcn_mfma_f32_16x16x32_f16(a, bf, acc[m], 0, 0, 0);
                            }
                        }
                    } else if (hprev) {
#pragma unroll
                        for (int m = 0; m < 4; ++m) {
                            f16x8 a = ldh8(hprev + (m * 16 + r) * HH + (k - EE) + kg * 8);
                            acc[m] = __builtin_amdgcn_mfma_f32_16x16x32_f16(a, bf, acc[m], 0, 0, 0);
                        }
                    }
                }
            } else {
                // ---------- layer 1, step tt:  A = [h0(tt) | h1(tt-1)] ----------
                const _Float16* h0cur  = hbuf0 + (tt & 1) * (BB * HH);
                const _Float16* h1prev = (tt > 0) ? h1buf + ((tt - 1) & 1) * (BB * HH) : nullptr;
                for (int i = 0; i < nchunk; ++i) {
                    const int k = kbase + i * 32;
                    const _Float16* Arow;
                    if (k < HH) Arow = h0cur + k;
                    else { if (!h1prev) break; Arow = h1prev + (k - HH); }
                    f16x8 bf = *reinterpret_cast<const f16x8*>(&Wlds[r * Kp + k + kg * 8]);
#pragma unroll
                    for (int m = 0; m < 4; ++m) {
                        f16x8 a = ldh8(Arow + (m * 16 + r) * HH + kg * 8);
                        acc[m] = __builtin_amdgcn_mfma_f32_16x16x32_f16(a, bf, acc[m], 0, 0, 0);
                    }
                }
            }

            // ---------- cross-wave reduce + epilogue ----------
#pragma unroll
            for (int m = 0; m < 4; ++m)
#pragma unroll
                for (int rr = 0; rr < 4; ++rr)
                    red[wave][m * 16 + kg * 4 + rr][r] = acc[m][rr];
            __syncthreads();
            {
                const int e = tid * 4;
                const int row = e >> 4, c = e & 15;
                f32x4 s = *reinterpret_cast<f32x4*>(&red[0][row][c]);
#pragma unroll
                for (int w = 1; w < 4; ++w) s += *reinterpret_cast<f32x4*>(&red[w][row][c]);
                const int nb = tile * 16 + c;
                const float* bp = bias + (isL1 ? 1024 : 0) + (dir ? 2048 : 0) + nb;
                float4 bv = *reinterpret_cast<const float4*>(bp);
                float v0 = tanhf(s[0] + bv.x), v1 = tanhf(s[1] + bv.y);
                float v2 = tanhf(s[2] + bv.z), v3 = tanhf(s[3] + bv.w);
                _Float16* hout = (isL1 ? h1buf : hbuf0) + (tt & 1) * (BB * HH) + row * HH + nb;
                f16x4 hv; hv[0] = (_Float16)v0; hv[1] = (_Float16)v1;
                hv[2] = (_Float16)v2; hv[3] = (_Float16)v3;
                *reinterpret_cast<f16x4*>(hout) = hv;
                if (isL1 && tt == SS - 1) {
                    float4 fv; fv.x = v0; fv.y = v1; fv.z = v2; fv.w = v3;
                    *reinterpret_cast<float4*>(h1fin + (size_t)dir * (BB * HH) + row * HH + nb) = fv;
                }
            }
        }
        if (t < SS) gridbar(ctr + t, 256u);
    }
}

// ---------- FC head (all fp32, runs once) ----------
__global__ void fc1_kernel(const float* __restrict__ h1fin, const float* __restrict__ w,
                           const float* __restrict__ b, float* __restrict__ v)
{
    int idx = blockIdx.x * 256 + threadIdx.x;   // (batch, out-feature)
    int bb = idx >> 6, nn = idx & 63;
    const float* hf = h1fin + bb * HH;
    const float* hb = h1fin + BB * HH + bb * HH;
    float s = b[nn];
#pragma unroll 8
    for (int k = 0; k < HH; ++k) s += hf[k] * w[k * 64 + nn];
#pragma unroll 8
    for (int k = 0; k < HH; ++k) s += hb[k] * w[(HH + k) * 64 + nn];
    v[idx] = s;
}

__global__ void fc2_kernel(const float* __restrict__ v, const float* __restrict__ w,
                           const float* __restrict__ b, float* __restrict__ out)
{
    int idx = threadIdx.x;
    if (idx >= BB * 2) return;
    int bb = idx >> 1, c = idx & 1;
    float s = b[c];
    const float* vb = v + bb * 64;
#pragma unroll
    for (int j = 0; j < 64; ++j) s += vb[j] * w[j * 2 + c];
    out[bb * 2 + c] = s;
}

extern "C" void kernel_launch(void* const* d_in, const int* in_sizes, int n_in,
                              void* d_out, int out_size, void* d_ws, size_t ws_size,
                              hipStream_t stream)
{
    const int*   x        = (const int*)  d_in[0];
    const float* emb      = (const float*)d_in[1];
    const float* fw0_wih  = (const float*)d_in[2];
    const float* fw0_bih  = (const float*)d_in[3];
    const float* fw0_whh  = (const float*)d_in[4];
    const float* fw0_bhh  = (const float*)d_in[5];
    const float* fw1_wih  = (const float*)d_in[6];
    const float* fw1_bih  = (const float*)d_in[7];
    const float* fw1_whh  = (const float*)d_in[8];
    const float* fw1_bhh  = (const float*)d_in[9];
    const float* bw0_wih  = (const float*)d_in[10];
    const float* bw0_bih  = (const float*)d_in[11];
    const float* bw0_whh  = (const float*)d_in[12];
    const float* bw0_bhh  = (const float*)d_in[13];
    const float* bw1_wih  = (const float*)d_in[14];
    const float* bw1_bih  = (const float*)d_in[15];
    const float* bw1_whh  = (const float*)d_in[16];
    const float* bw1_bhh  = (const float*)d_in[17];
    const float* fc1_w    = (const float*)d_in[18];
    const float* fc1_b    = (const float*)d_in[19];
    const float* fc2_w    = (const float*)d_in[20];
    const float* fc2_b    = (const float*)d_in[21];

    size_t off = 0;
    char* wsb = (char*)d_ws;
    auto take = [&](size_t bytes) -> void* {
        void* p = wsb + off;
        off += (bytes + 255) & ~(size_t)255;
        return p;
    };
    _Float16* W0f   = (_Float16*)take((size_t)HH * 1536 * 2);
    _Float16* W1f   = (_Float16*)take((size_t)HH * 2048 * 2);
    _Float16* W0b   = (_Float16*)take((size_t)HH * 1536 * 2);
    _Float16* W1b   = (_Float16*)take((size_t)HH * 2048 * 2);
    float*    bias  = (float*)   take(4096 * 4);
    _Float16* h0f   = (_Float16*)take((size_t)2 * BB * HH * 2);
    _Float16* h1f   = (_Float16*)take((size_t)2 * BB * HH * 2);
    _Float16* h0b   = (_Float16*)take((size_t)2 * BB * HH * 2);
    _Float16* h1b   = (_Float16*)take((size_t)2 * BB * HH * 2);
    float*    h1fin = (float*)   take((size_t)2 * BB * HH * 4);
    float*    vmid  = (float*)   take(4096 * 4);
    unsigned* ctr   = (unsigned*)take(512 * 4);
    size_t base_need = off;
    _Float16* embx  = (_Float16*)take((size_t)SS * BB * EE * 2);   // 32 MB
    bool use_embx = (ws_size >= off);
    (void)base_need;

    prep_wt<<<HH, 256, 0, stream>>>(fw0_wih, fw0_whh, EE, HH, W0f);
    prep_wt<<<HH, 256, 0, stream>>>(fw1_wih, fw1_whh, HH, HH, W1f);
    prep_wt<<<HH, 256, 0, stream>>>(bw0_wih, bw0_whh, EE, HH, W0b);
    prep_wt<<<HH, 256, 0, stream>>>(bw1_wih, bw1_whh, HH, HH, W1b);
    prep_bias<<<1, 1024, 0, stream>>>(fw0_bih, fw0_bhh, fw1_bih, fw1_bhh,
                                      bw0_bih, bw0_bhh, bw1_bih, bw1_bhh, bias);
    if (use_embx)
        prep_embx<<<SS * BB, 128, 0, stream>>>(x, emb, embx);
    hipMemsetAsync(ctr, 0, 512 * 4, stream);

    const _Float16* embx_arg = use_embx ? embx : nullptr;
    void* args[] = {(void*)&x, (void*)&emb, (void*)&embx_arg,
                    (void*)&W0f, (void*)&W1f, (void*)&W0b, (void*)&W1b,
                    (void*)&bias, (void*)&h0f, (void*)&h1f, (void*)&h0b, (void*)&h1b,
                    (void*)&h1fin, (void*)&ctr};
    hipLaunchCooperativeKernel((void*)rnn_persistent, dim3(256), dim3(256), args, 0, stream);

    fc1_kernel<<<16, 256, 0, stream>>>(h1fin, fc1_w, fc1_b, vmid);
    fc2_kernel<<<1, 128, 0, stream>>>(vmid, fc2_w, fc2_b, (float*)d_out);
}

// Round 3
// 11858.856 us; speedup vs baseline: 1.7025x; 1.4453x over previous
//
#include <hip/hip_runtime.h>
#include <hip/hip_bf16.h>
#include <hip/hip_fp16.h>

#define SS 512
#define BB 64
#define EE 512
#define HH 1024

typedef _Float16 f16x8 __attribute__((ext_vector_type(8)));
typedef _Float16 f16x4 __attribute__((ext_vector_type(4)));
typedef float f32x4 __attribute__((ext_vector_type(4)));

__device__ __forceinline__ f16x8 ldh8(const _Float16* p) {
    return *reinterpret_cast<const f16x8*>(p);
}

// ---------- prep: [K1+K2][HH] fp32 (wih over whh) -> [HH][K] fp16, coalesced reads ----------
__global__ void prep_wt(const float* __restrict__ wih, const float* __restrict__ whh,
                        int K1, int K, _Float16* __restrict__ out)
{
    int k = blockIdx.x;                // source row (input feature)
    const float* src = (k < K1) ? (wih + (size_t)k * HH) : (whh + (size_t)(k - K1) * HH);
    for (int n = threadIdx.x; n < HH; n += blockDim.x)
        out[(size_t)n * K + k] = (_Float16)src[n];
}

// bias layout: [0]=L0 fwd, [1024]=L1 fwd, [2048]=L0 bwd, [3072]=L1 bwd (bih+bhh combined)
__global__ void prep_bias(const float* f0ih, const float* f0hh,
                          const float* f1ih, const float* f1hh,
                          const float* b0ih, const float* b0hh,
                          const float* b1ih, const float* b1hh,
                          float* __restrict__ bias)
{
    int i = threadIdx.x;
    bias[i]          = f0ih[i] + f0hh[i];
    bias[1024 + i]   = f1ih[i] + f1hh[i];
    bias[2048 + i]   = b0ih[i] + b0hh[i];
    bias[3072 + i]   = b1ih[i] + b1hh[i];
}

// ---------- embedding pre-gather: embx[t][b][e] = fp16(emb[x[b][t]][e]) ----------
__global__ void prep_embx(const int* __restrict__ x, const float* __restrict__ emb,
                          _Float16* __restrict__ embx)
{
    int t = blockIdx.x >> 6, b = blockIdx.x & 63;
    const float* src = emb + (size_t)x[b * SS + t] * EE;
    _Float16* dst = embx + ((size_t)t * BB + b) * EE;
    int i = threadIdx.x * 4;            // 128 threads * 4 = 512
    float4 v = *reinterpret_cast<const float4*>(src + i);
    f16x4 h;
    h[0] = (_Float16)v.x; h[1] = (_Float16)v.y;
    h[2] = (_Float16)v.z; h[3] = (_Float16)v.w;
    *reinterpret_cast<f16x4*>(dst + i) = h;
}

// ---------- dataflow sync helpers ----------
// Counters: 4 chains (L0f, L0b, L1f, L1b) x SS steps, each counter on its own 64B line.
__device__ __forceinline__ void wait_counters(const unsigned* a, const unsigned* b)
{
    if (!a && !b) return;
    if (threadIdx.x == 0) {
        for (;;) {
            bool ok = true;
            if (a && __hip_atomic_load(a, __ATOMIC_RELAXED, __HIP_MEMORY_SCOPE_AGENT) < 64u)
                ok = false;
            if (ok && b && __hip_atomic_load(b, __ATOMIC_RELAXED, __HIP_MEMORY_SCOPE_AGENT) < 64u)
                ok = false;
            if (ok) break;
            __builtin_amdgcn_s_sleep(2);
        }
        __builtin_amdgcn_fence(__ATOMIC_ACQUIRE, "agent");   // inv L1 + XCD L2
    }
    __syncthreads();
}

__device__ __forceinline__ void publish(unsigned* c)
{
    __syncthreads();                   // drains all waves' vmcnt (stores in L2)
    if (threadIdx.x == 0) {
        __builtin_amdgcn_fence(__ATOMIC_RELEASE, "agent");   // wbl2: flush dirty L2
        atomicAdd(c, 1u);
    }
}

// ---------- persistent RNN kernel ----------
// 256 blocks: task = bid>>6 (0:L0f 1:L0b 2:L1f 3:L1b), tile = bid&63 -> 16 output cols.
// Weights live in LDS; 4 waves split K; LDS cross-wave reduce; dataflow sync between groups.
__global__ __launch_bounds__(256, 1)
void rnn_persistent(const int* __restrict__ x, const float* __restrict__ emb,
                    const _Float16* __restrict__ embx,          // may be null -> gather in-loop
                    const _Float16* __restrict__ W0f, const _Float16* __restrict__ W1f,
                    const _Float16* __restrict__ W0b, const _Float16* __restrict__ W1b,
                    const float* __restrict__ bias,
                    _Float16* __restrict__ h0f, _Float16* __restrict__ h1f,
                    _Float16* __restrict__ h0b, _Float16* __restrict__ h1b,
                    float* __restrict__ h1fin, unsigned* __restrict__ ctr)
{
    const int bid  = blockIdx.x;
    const int task = bid >> 6;
    const int tile = bid & 63;
    const int dir  = task & 1;
    const bool isL1 = task >= 2;
    const int lane = threadIdx.x & 63;
    const int wave = threadIdx.x >> 6;
    const int r    = lane & 15;       // output col within tile / A row within 16-frag
    const int kg   = lane >> 4;       // k-group (8 halves)
    const int tid  = threadIdx.x;

    const int K  = isL1 ? 2048 : 1536;
    const int Kp = K + 24;            // LDS row stride (halves): 2-way banks on b128 reads

    __shared__ _Float16 Wlds[16 * 2072];      // 66,304 B
    __shared__ float red[4][64][20];          // 20,480 B (padded: 2-way banks)

    // --- stage this block's weight slice into LDS (once) ---
    {
        const _Float16* Wg = isL1 ? (dir ? W1b : W1f) : (dir ? W0b : W0f);
        int rowlen = K >> 3;
        for (int idx = tid; idx < 16 * rowlen; idx += 256) {
            int row = idx / rowlen, kk = (idx - row * rowlen) * 8;
            f16x8 v = ldh8(Wg + (size_t)(tile * 16 + row) * K + kk);
            *reinterpret_cast<f16x8*>(&Wlds[row * Kp + kk]) = v;
        }
    }
    __syncthreads();

    _Float16* hbuf0 = dir ? h0b : h0f;        // layer0 state ping-pong [2][64][1024]
    _Float16* h1buf = dir ? h1b : h1f;

    // counter bases (16 uints = 64B per step)
    unsigned* c_L0 = ctr + (size_t)dir * SS * 16;
    unsigned* c_L1 = ctr + (size_t)(2 + dir) * SS * 16;

    for (int t = 0; t < SS; ++t) {
        f32x4 acc[4];
#pragma unroll
        for (int m = 0; m < 4; ++m) acc[m] = (f32x4){0.f, 0.f, 0.f, 0.f};

        if (!isL1) {
            // ===== layer 0, step t : A = [embx(t_eff) | h0(t-1)] =====
            const int t_eff = dir ? (SS - 1 - t) : t;
            // --- emb segment (independent of recurrence): wave covers [wave*128, +128)
            if (embx) {
                const _Float16* Aemb = embx + (size_t)t_eff * (BB * EE);
#pragma unroll
                for (int i = 0; i < 4; ++i) {
                    const int k = wave * 128 + i * 32;
                    f16x8 bf = *reinterpret_cast<const f16x8*>(&Wlds[r * Kp + k + kg * 8]);
#pragma unroll
                    for (int m = 0; m < 4; ++m) {
                        f16x8 a = ldh8(Aemb + (m * 16 + r) * EE + k + kg * 8);
                        acc[m] = __builtin_amdgcn_mfma_f32_16x16x32_f16(a, bf, acc[m], 0, 0, 0);
                    }
                }
            } else {
                const float* erow[4];
#pragma unroll
                for (int m = 0; m < 4; ++m)
                    erow[m] = emb + (size_t)x[(m * 16 + r) * SS + t_eff] * EE;
#pragma unroll
                for (int i = 0; i < 4; ++i) {
                    const int k = wave * 128 + i * 32;
                    f16x8 bf = *reinterpret_cast<const f16x8*>(&Wlds[r * Kp + k + kg * 8]);
#pragma unroll
                    for (int m = 0; m < 4; ++m) {
                        const float* p = erow[m] + k + kg * 8;
                        float4 lo = *reinterpret_cast<const float4*>(p);
                        float4 hi = *reinterpret_cast<const float4*>(p + 4);
                        f16x8 a;
                        a[0] = (_Float16)lo.x; a[1] = (_Float16)lo.y;
                        a[2] = (_Float16)lo.z; a[3] = (_Float16)lo.w;
                        a[4] = (_Float16)hi.x; a[5] = (_Float16)hi.y;
                        a[6] = (_Float16)hi.z; a[7] = (_Float16)hi.w;
                        acc[m] = __builtin_amdgcn_mfma_f32_16x16x32_f16(a, bf, acc[m], 0, 0, 0);
                    }
                }
            }
            // --- wait: h0(t-1) published; h0 slot t&1 (=h0(t-2)) free of L1 readers
            wait_counters(t >= 1 ? c_L0 + (size_t)(t - 1) * 16 : nullptr,
                          t >= 2 ? c_L1 + (size_t)(t - 2) * 16 : nullptr);
            // --- h segment: wave covers [wave*256, +256)
            if (t > 0) {
                const _Float16* hprev = hbuf0 + ((t - 1) & 1) * (BB * HH);
#pragma unroll
                for (int i = 0; i < 8; ++i) {
                    const int k = wave * 256 + i * 32;
                    f16x8 bf = *reinterpret_cast<const f16x8*>(&Wlds[r * Kp + EE + k + kg * 8]);
#pragma unroll
                    for (int m = 0; m < 4; ++m) {
                        f16x8 a = ldh8(hprev + (m * 16 + r) * HH + k + kg * 8);
                        acc[m] = __builtin_amdgcn_mfma_f32_16x16x32_f16(a, bf, acc[m], 0, 0, 0);
                    }
                }
            }
        } else {
            // ===== layer 1, step t : A = [h0(t) | h1(t-1)] =====
            wait_counters(c_L0 + (size_t)t * 16,
                          t >= 1 ? c_L1 + (size_t)(t - 1) * 16 : nullptr);
            const _Float16* h0cur = hbuf0 + (t & 1) * (BB * HH);
#pragma unroll
            for (int i = 0; i < 8; ++i) {
                const int k = wave * 256 + i * 32;
                f16x8 bf = *reinterpret_cast<const f16x8*>(&Wlds[r * Kp + k + kg * 8]);
#pragma unroll
                for (int m = 0; m < 4; ++m) {
                    f16x8 a = ldh8(h0cur + (m * 16 + r) * HH + k + kg * 8);
                    acc[m] = __builtin_amdgcn_mfma_f32_16x16x32_f16(a, bf, acc[m], 0, 0, 0);
                }
            }
            if (t > 0) {
                const _Float16* h1prev = h1buf + ((t - 1) & 1) * (BB * HH);
#pragma unroll
                for (int i = 0; i < 8; ++i) {
                    const int k = wave * 256 + i * 32;
                    f16x8 bf = *reinterpret_cast<const f16x8*>(&Wlds[r * Kp + HH + k + kg * 8]);
#pragma unroll
                    for (int m = 0; m < 4; ++m) {
                        f16x8 a = ldh8(h1prev + (m * 16 + r) * HH + k + kg * 8);
                        acc[m] = __builtin_amdgcn_mfma_f32_16x16x32_f16(a, bf, acc[m], 0, 0, 0);
                    }
                }
            }
        }

        // ---------- cross-wave reduce + epilogue ----------
#pragma unroll
        for (int m = 0; m < 4; ++m)
#pragma unroll
            for (int rr = 0; rr < 4; ++rr)
                red[wave][m * 16 + kg * 4 + rr][r] = acc[m][rr];
        __syncthreads();
        {
            const int row = tid >> 2;          // 0..63
            const int c   = (tid & 3) * 4;     // 0,4,8,12
            f32x4 s = *reinterpret_cast<f32x4*>(&red[0][row][c]);
#pragma unroll
            for (int w = 1; w < 4; ++w) s += *reinterpret_cast<f32x4*>(&red[w][row][c]);
            const int nb = tile * 16 + c;
            const float* bp = bias + (isL1 ? 1024 : 0) + (dir ? 2048 : 0) + nb;
            float4 bv = *reinterpret_cast<const float4*>(bp);
            float v0 = tanhf(s[0] + bv.x), v1 = tanhf(s[1] + bv.y);
            float v2 = tanhf(s[2] + bv.z), v3 = tanhf(s[3] + bv.w);
            _Float16* hout = (isL1 ? h1buf : hbuf0) + (t & 1) * (BB * HH) + row * HH + nb;
            f16x4 hv; hv[0] = (_Float16)v0; hv[1] = (_Float16)v1;
            hv[2] = (_Float16)v2; hv[3] = (_Float16)v3;
            *reinterpret_cast<f16x4*>(hout) = hv;
            if (isL1 && t == SS - 1) {
                float4 fv; fv.x = v0; fv.y = v1; fv.z = v2; fv.w = v3;
                *reinterpret_cast<float4*>(h1fin + (size_t)dir * (BB * HH) + row * HH + nb) = fv;
            }
        }
        publish((isL1 ? c_L1 : c_L0) + (size_t)t * 16);
    }
}

// ---------- FC head (all fp32, runs once) ----------
__global__ void fc1_kernel(const float* __restrict__ h1fin, const float* __restrict__ w,
                           const float* __restrict__ b, float* __restrict__ v)
{
    int idx = blockIdx.x * 256 + threadIdx.x;   // (batch, out-feature)
    int bb = idx >> 6, nn = idx & 63;
    const float* hf = h1fin + bb * HH;
    const float* hb = h1fin + BB * HH + bb * HH;
    float s = b[nn];
#pragma unroll 8
    for (int k = 0; k < HH; ++k) s += hf[k] * w[k * 64 + nn];
#pragma unroll 8
    for (int k = 0; k < HH; ++k) s += hb[k] * w[(HH + k) * 64 + nn];
    v[idx] = s;
}

__global__ void fc2_kernel(const float* __restrict__ v, const float* __restrict__ w,
                           const float* __restrict__ b, float* __restrict__ out)
{
    int idx = threadIdx.x;
    if (idx >= BB * 2) return;
    int bb = idx >> 1, c = idx & 1;
    float s = b[c];
    const float* vb = v + bb * 64;
#pragma unroll
    for (int j = 0; j < 64; ++j) s += vb[j] * w[j * 2 + c];
    out[bb * 2 + c] = s;
}

extern "C" void kernel_launch(void* const* d_in, const int* in_sizes, int n_in,
                              void* d_out, int out_size, void* d_ws, size_t ws_size,
                              hipStream_t stream)
{
    const int*   x        = (const int*)  d_in[0];
    const float* emb      = (const float*)d_in[1];
    const float* fw0_wih  = (const float*)d_in[2];
    const float* fw0_bih  = (const float*)d_in[3];
    const float* fw0_whh  = (const float*)d_in[4];
    const float* fw0_bhh  = (const float*)d_in[5];
    const float* fw1_wih  = (const float*)d_in[6];
    const float* fw1_bih  = (const float*)d_in[7];
    const float* fw1_whh  = (const float*)d_in[8];
    const float* fw1_bhh  = (const float*)d_in[9];
    const float* bw0_wih  = (const float*)d_in[10];
    const float* bw0_bih  = (const float*)d_in[11];
    const float* bw0_whh  = (const float*)d_in[12];
    const float* bw0_bhh  = (const float*)d_in[13];
    const float* bw1_wih  = (const float*)d_in[14];
    const float* bw1_bih  = (const float*)d_in[15];
    const float* bw1_whh  = (const float*)d_in[16];
    const float* bw1_bhh  = (const float*)d_in[17];
    const float* fc1_w    = (const float*)d_in[18];
    const float* fc1_b    = (const float*)d_in[19];
    const float* fc2_w    = (const float*)d_in[20];
    const float* fc2_b    = (const float*)d_in[21];

    size_t off = 0;
    char* wsb = (char*)d_ws;
    auto take = [&](size_t bytes) -> void* {
        void* p = wsb + off;
        off += (bytes + 255) & ~(size_t)255;
        return p;
    };
    _Float16* W0f   = (_Float16*)take((size_t)HH * 1536 * 2);
    _Float16* W1f   = (_Float16*)take((size_t)HH * 2048 * 2);
    _Float16* W0b   = (_Float16*)take((size_t)HH * 1536 * 2);
    _Float16* W1b   = (_Float16*)take((size_t)HH * 2048 * 2);
    float*    bias  = (float*)   take(4096 * 4);
    _Float16* h0f   = (_Float16*)take((size_t)2 * BB * HH * 2);
    _Float16* h1f   = (_Float16*)take((size_t)2 * BB * HH * 2);
    _Float16* h0b   = (_Float16*)take((size_t)2 * BB * HH * 2);
    _Float16* h1b   = (_Float16*)take((size_t)2 * BB * HH * 2);
    float*    h1fin = (float*)   take((size_t)2 * BB * HH * 4);
    float*    vmid  = (float*)   take(4096 * 4);
    unsigned* ctr   = (unsigned*)take((size_t)4 * SS * 16 * 4);   // 4 chains x SS x 64B
    _Float16* embx  = (_Float16*)take((size_t)SS * BB * EE * 2);  // 32 MB
    bool use_embx = (ws_size >= off);

    prep_wt<<<1536, 256, 0, stream>>>(fw0_wih, fw0_whh, EE, 1536, W0f);
    prep_wt<<<2048, 256, 0, stream>>>(fw1_wih, fw1_whh, HH, 2048, W1f);
    prep_wt<<<1536, 256, 0, stream>>>(bw0_wih, bw0_whh, EE, 1536, W0b);
    prep_wt<<<2048, 256, 0, stream>>>(bw1_wih, bw1_whh, HH, 2048, W1b);
    prep_bias<<<1, 1024, 0, stream>>>(fw0_bih, fw0_bhh, fw1_bih, fw1_bhh,
                                      bw0_bih, bw0_bhh, bw1_bih, bw1_bhh, bias);
    if (use_embx)
        prep_embx<<<SS * BB, 128, 0, stream>>>(x, emb, embx);
    hipMemsetAsync(ctr, 0, (size_t)4 * SS * 16 * 4, stream);

    const _Float16* embx_arg = use_embx ? embx : nullptr;
    void* args[] = {(void*)&x, (void*)&emb, (void*)&embx_arg,
                    (void*)&W0f, (void*)&W1f, (void*)&W0b, (void*)&W1b,
                    (void*)&bias, (void*)&h0f, (void*)&h1f, (void*)&h0b, (void*)&h1b,
                    (void*)&h1fin, (void*)&ctr};
    hipLaunchCooperativeKernel((void*)rnn_persistent, dim3(256), dim3(256), args, 0, stream);

    fc1_kernel<<<16, 256, 0, stream>>>(h1fin, fc1_w, fc1_b, vmid);
    fc2_kernel<<<1, 128, 0, stream>>>(vmid, fc2_w, fc2_b, (float*)d_out);
}

// Round 4
// 5500.282 us; speedup vs baseline: 3.6706x; 2.1560x over previous
//
#include <hip/hip_runtime.h>
#include <hip/hip_bf16.h>
#include <hip/hip_fp16.h>

#define SS 512
#define BB 64
#define EE 512
#define HH 1024

typedef _Float16 f16x8 __attribute__((ext_vector_type(8)));
typedef _Float16 f16x4 __attribute__((ext_vector_type(4)));
typedef float f32x4 __attribute__((ext_vector_type(4)));
typedef unsigned long long u64;

__device__ __forceinline__ f16x8 ldh8(const _Float16* p) {
    return *reinterpret_cast<const f16x8*>(p);
}

// ---------- prep: [K1+K2][HH] fp32 (wih over whh) -> [HH][K] fp16, coalesced reads ----------
__global__ void prep_wt(const float* __restrict__ wih, const float* __restrict__ whh,
                        int K1, int K, _Float16* __restrict__ out)
{
    int k = blockIdx.x;                // source row (input feature)
    const float* src = (k < K1) ? (wih + (size_t)k * HH) : (whh + (size_t)(k - K1) * HH);
    for (int n = threadIdx.x; n < HH; n += blockDim.x)
        out[(size_t)n * K + k] = (_Float16)src[n];
}

// bias layout: [0]=L0 fwd, [1024]=L1 fwd, [2048]=L0 bwd, [3072]=L1 bwd (bih+bhh combined)
__global__ void prep_bias(const float* f0ih, const float* f0hh,
                          const float* f1ih, const float* f1hh,
                          const float* b0ih, const float* b0hh,
                          const float* b1ih, const float* b1hh,
                          float* __restrict__ bias)
{
    int i = threadIdx.x;
    bias[i]          = f0ih[i] + f0hh[i];
    bias[1024 + i]   = f1ih[i] + f1hh[i];
    bias[2048 + i]   = b0ih[i] + b0hh[i];
    bias[3072 + i]   = b1ih[i] + b1hh[i];
}

// ---------- embedding pre-gather: embx[t][b][e] = fp16(emb[x[b][t]][e]) ----------
__global__ void prep_embx(const int* __restrict__ x, const float* __restrict__ emb,
                          _Float16* __restrict__ embx)
{
    int t = blockIdx.x >> 6, b = blockIdx.x & 63;
    const float* src = emb + (size_t)x[b * SS + t] * EE;
    _Float16* dst = embx + ((size_t)t * BB + b) * EE;
    int i = threadIdx.x * 4;            // 128 threads * 4 = 512
    float4 v = *reinterpret_cast<const float4*>(src + i);
    f16x4 h;
    h[0] = (_Float16)v.x; h[1] = (_Float16)v.y;
    h[2] = (_Float16)v.z; h[3] = (_Float16)v.w;
    *reinterpret_cast<f16x4*>(dst + i) = h;
}

// ---------- fragment-tiled h state, accessed only via agent-scope (L3) atomics ----------
// half-index(row,col) = (col>>5)*2048 + (row>>4)*512 + ((col>>3)&3)*128 + (row&15)*8 + (col&7)
// slot = 64x1024 halves = 16384 u64.
__device__ __forceinline__ f16x8 ld_tile(const u64* __restrict__ slot, int k0, int m, int kg, int r)
{
    union { u64 u[2]; f16x8 v; } z;
    const u64* p = slot + ((k0 >> 5) * 512 + m * 128 + kg * 32 + r * 2);
    z.u[0] = __hip_atomic_load(p,     __ATOMIC_RELAXED, __HIP_MEMORY_SCOPE_AGENT);
    z.u[1] = __hip_atomic_load(p + 1, __ATOMIC_RELAXED, __HIP_MEMORY_SCOPE_AGENT);
    return z.v;
}

__device__ __forceinline__ void st_tile(u64* __restrict__ slot, int row, int col4, f16x4 hv)
{
    union { u64 u; f16x4 v; } z; z.v = hv;
    u64* p = slot + ((col4 >> 5) * 512 + (row >> 4) * 128 + ((col4 >> 3) & 3) * 32
                     + (row & 15) * 2 + ((col4 >> 2) & 1));
    __hip_atomic_store(p, z.u, __ATOMIC_RELAXED, __HIP_MEMORY_SCOPE_AGENT);
}

// ---------- dataflow sync: per (chain, step) 4 sub-counters on 4 cache lines ----------
__device__ __forceinline__ bool ctr_done(const unsigned* c)
{
#pragma unroll
    for (int j = 0; j < 4; ++j)
        if (__hip_atomic_load(c + j * 16, __ATOMIC_RELAXED, __HIP_MEMORY_SCOPE_AGENT) < 16u)
            return false;
    return true;
}

__device__ __forceinline__ void wait_counters(const unsigned* a, const unsigned* b)
{
    if (!a && !b) return;
    if (threadIdx.x == 0) {
        for (;;) {
            bool ok = true;
            if (a) ok = ctr_done(a);
            if (ok && b) ok = ctr_done(b);
            if (ok) break;
            __builtin_amdgcn_s_sleep(1);
        }
    }
    __syncthreads();
}

__device__ __forceinline__ void publish(unsigned* c, int sub)
{
    __syncthreads();   // compiler emits s_waitcnt vmcnt(0) before s_barrier: all sc1 stores at L3
    if (threadIdx.x == 0)
        atomicAdd(c + sub * 16, 1u);
}

// ---------- persistent RNN kernel ----------
// 256 blocks: task = bid>>6 (0:L0f 1:L0b 2:L1f 3:L1b), tile = bid&63 -> 16 output cols.
// Weights in LDS; 4 waves split K; LDS cross-wave reduce; L3-atomic dataflow (no fences).
__global__ __launch_bounds__(256, 1)
void rnn_persistent(const int* __restrict__ x, const float* __restrict__ emb,
                    const _Float16* __restrict__ embx,          // may be null -> gather in-loop
                    const _Float16* __restrict__ W0f, const _Float16* __restrict__ W1f,
                    const _Float16* __restrict__ W0b, const _Float16* __restrict__ W1b,
                    const float* __restrict__ bias,
                    u64* __restrict__ h0f, u64* __restrict__ h1f,
                    u64* __restrict__ h0b, u64* __restrict__ h1b,
                    float* __restrict__ h1fin, unsigned* __restrict__ ctr)
{
    const int bid  = blockIdx.x;
    const int task = bid >> 6;
    const int tile = bid & 63;
    const int dir  = task & 1;
    const bool isL1 = task >= 2;
    const int lane = threadIdx.x & 63;
    const int wave = threadIdx.x >> 6;
    const int r    = lane & 15;       // output col within tile / A row within 16-frag
    const int kg   = lane >> 4;       // k-group (8 halves)
    const int tid  = threadIdx.x;

    const int K  = isL1 ? 2048 : 1536;
    const int Kp = K + 24;            // LDS row stride (halves)

    __shared__ _Float16 Wlds[16 * 2072];      // 66,304 B
    __shared__ float red[4][64][20];          // 20,480 B

    // --- stage this block's weight slice into LDS (once) ---
    {
        const _Float16* Wg = isL1 ? (dir ? W1b : W1f) : (dir ? W0b : W0f);
        int rowlen = K >> 3;
        for (int idx = tid; idx < 16 * rowlen; idx += 256) {
            int row = idx / rowlen, kk = (idx - row * rowlen) * 8;
            f16x8 v = ldh8(Wg + (size_t)(tile * 16 + row) * K + kk);
            *reinterpret_cast<f16x8*>(&Wlds[row * Kp + kk]) = v;
        }
    }
    __syncthreads();

    u64* hbuf0 = dir ? h0b : h0f;     // layer0 state ping-pong [2][16384] u64
    u64* h1buf = dir ? h1b : h1f;

    // counter bases: 64 uints (4 lines) per (chain, step)
    unsigned* c_L0 = ctr + (size_t)dir * SS * 64;
    unsigned* c_L1 = ctr + (size_t)(2 + dir) * SS * 64;
    const int sub = tile & 3;

    for (int t = 0; t < SS; ++t) {
        f32x4 acc[4];
#pragma unroll
        for (int m = 0; m < 4; ++m) acc[m] = (f32x4){0.f, 0.f, 0.f, 0.f};

        if (!isL1) {
            // ===== layer 0, step t : A = [embx(t_eff) | h0(t-1)] =====
            const int t_eff = dir ? (SS - 1 - t) : t;
            // --- emb segment (independent of recurrence): wave covers [wave*128, +128)
            if (embx) {
                const _Float16* Aemb = embx + (size_t)t_eff * (BB * EE);
#pragma unroll
                for (int i = 0; i < 4; ++i) {
                    const int k = wave * 128 + i * 32;
                    f16x8 bf = *reinterpret_cast<const f16x8*>(&Wlds[r * Kp + k + kg * 8]);
#pragma unroll
                    for (int m = 0; m < 4; ++m) {
                        f16x8 a = ldh8(Aemb + (m * 16 + r) * EE + k + kg * 8);
                        acc[m] = __builtin_amdgcn_mfma_f32_16x16x32_f16(a, bf, acc[m], 0, 0, 0);
                    }
                }
            } else {
                const float* erow[4];
#pragma unroll
                for (int m = 0; m < 4; ++m)
                    erow[m] = emb + (size_t)x[(m * 16 + r) * SS + t_eff] * EE;
#pragma unroll
                for (int i = 0; i < 4; ++i) {
                    const int k = wave * 128 + i * 32;
                    f16x8 bf = *reinterpret_cast<const f16x8*>(&Wlds[r * Kp + k + kg * 8]);
#pragma unroll
                    for (int m = 0; m < 4; ++m) {
                        const float* p = erow[m] + k + kg * 8;
                        float4 lo = *reinterpret_cast<const float4*>(p);
                        float4 hi = *reinterpret_cast<const float4*>(p + 4);
                        f16x8 a;
                        a[0] = (_Float16)lo.x; a[1] = (_Float16)lo.y;
                        a[2] = (_Float16)lo.z; a[3] = (_Float16)lo.w;
                        a[4] = (_Float16)hi.x; a[5] = (_Float16)hi.y;
                        a[6] = (_Float16)hi.z; a[7] = (_Float16)hi.w;
                        acc[m] = __builtin_amdgcn_mfma_f32_16x16x32_f16(a, bf, acc[m], 0, 0, 0);
                    }
                }
            }
            // --- wait: h0(t-1) data ready; h0 slot t&1 (=h0(t-2)) free of L1 readers
            wait_counters(t >= 1 ? c_L0 + (size_t)(t - 1) * 64 : nullptr,
                          t >= 2 ? c_L1 + (size_t)(t - 2) * 64 : nullptr);
            // --- h segment: wave covers [wave*256, +256)
            if (t > 0) {
                const u64* hprev = hbuf0 + ((t - 1) & 1) * 16384;
#pragma unroll
                for (int i = 0; i < 8; ++i) {
                    const int k = wave * 256 + i * 32;
                    f16x8 bf = *reinterpret_cast<const f16x8*>(&Wlds[r * Kp + EE + k + kg * 8]);
#pragma unroll
                    for (int m = 0; m < 4; ++m) {
                        f16x8 a = ld_tile(hprev, k, m, kg, r);
                        acc[m] = __builtin_amdgcn_mfma_f32_16x16x32_f16(a, bf, acc[m], 0, 0, 0);
                    }
                }
            }
        } else {
            // ===== layer 1, step t : A = [h0(t) | h1(t-1)] =====
            wait_counters(c_L0 + (size_t)t * 64,
                          t >= 1 ? c_L1 + (size_t)(t - 1) * 64 : nullptr);
            const u64* h0cur = hbuf0 + (t & 1) * 16384;
#pragma unroll
            for (int i = 0; i < 8; ++i) {
                const int k = wave * 256 + i * 32;
                f16x8 bf = *reinterpret_cast<const f16x8*>(&Wlds[r * Kp + k + kg * 8]);
#pragma unroll
                for (int m = 0; m < 4; ++m) {
                    f16x8 a = ld_tile(h0cur, k, m, kg, r);
                    acc[m] = __builtin_amdgcn_mfma_f32_16x16x32_f16(a, bf, acc[m], 0, 0, 0);
                }
            }
            if (t > 0) {
                const u64* h1prev = h1buf + ((t - 1) & 1) * 16384;
#pragma unroll
                for (int i = 0; i < 8; ++i) {
                    const int k = wave * 256 + i * 32;
                    f16x8 bf = *reinterpret_cast<const f16x8*>(&Wlds[r * Kp + HH + k + kg * 8]);
#pragma unroll
                    for (int m = 0; m < 4; ++m) {
                        f16x8 a = ld_tile(h1prev, k, m, kg, r);
                        acc[m] = __builtin_amdgcn_mfma_f32_16x16x32_f16(a, bf, acc[m], 0, 0, 0);
                    }
                }
            }
        }

        // ---------- cross-wave reduce + epilogue ----------
#pragma unroll
        for (int m = 0; m < 4; ++m)
#pragma unroll
            for (int rr = 0; rr < 4; ++rr)
                red[wave][m * 16 + kg * 4 + rr][r] = acc[m][rr];
        __syncthreads();
        {
            const int row = tid >> 2;          // 0..63
            const int c   = (tid & 3) * 4;     // 0,4,8,12
            f32x4 s = *reinterpret_cast<f32x4*>(&red[0][row][c]);
#pragma unroll
            for (int w = 1; w < 4; ++w) s += *reinterpret_cast<f32x4*>(&red[w][row][c]);
            const int nb = tile * 16 + c;
            const float* bp = bias + (isL1 ? 1024 : 0) + (dir ? 2048 : 0) + nb;
            float4 bv = *reinterpret_cast<const float4*>(bp);
            float v0 = tanhf(s[0] + bv.x), v1 = tanhf(s[1] + bv.y);
            float v2 = tanhf(s[2] + bv.z), v3 = tanhf(s[3] + bv.w);
            f16x4 hv; hv[0] = (_Float16)v0; hv[1] = (_Float16)v1;
            hv[2] = (_Float16)v2; hv[3] = (_Float16)v3;
            u64* hout = (isL1 ? h1buf : hbuf0) + (t & 1) * 16384;
            st_tile(hout, row, nb, hv);
            if (isL1 && t == SS - 1) {
                float4 fv; fv.x = v0; fv.y = v1; fv.z = v2; fv.w = v3;
                *reinterpret_cast<float4*>(h1fin + (size_t)dir * (BB * HH) + row * HH + nb) = fv;
            }
        }
        publish((isL1 ? c_L1 : c_L0) + (size_t)t * 64, sub);
    }
}

// ---------- FC head (all fp32, runs once) ----------
__global__ void fc1_kernel(const float* __restrict__ h1fin, const float* __restrict__ w,
                           const float* __restrict__ b, float* __restrict__ v)
{
    int idx = blockIdx.x * 256 + threadIdx.x;   // (batch, out-feature)
    int bb = idx >> 6, nn = idx & 63;
    const float* hf = h1fin + bb * HH;
    const float* hb = h1fin + BB * HH + bb * HH;
    float s = b[nn];
#pragma unroll 8
    for (int k = 0; k < HH; ++k) s += hf[k] * w[k * 64 + nn];
#pragma unroll 8
    for (int k = 0; k < HH; ++k) s += hb[k] * w[(HH + k) * 64 + nn];
    v[idx] = s;
}

__global__ void fc2_kernel(const float* __restrict__ v, const float* __restrict__ w,
                           const float* __restrict__ b, float* __restrict__ out)
{
    int idx = threadIdx.x;
    if (idx >= BB * 2) return;
    int bb = idx >> 1, c = idx & 1;
    float s = b[c];
    const float* vb = v + bb * 64;
#pragma unroll
    for (int j = 0; j < 64; ++j) s += vb[j] * w[j * 2 + c];
    out[bb * 2 + c] = s;
}

extern "C" void kernel_launch(void* const* d_in, const int* in_sizes, int n_in,
                              void* d_out, int out_size, void* d_ws, size_t ws_size,
                              hipStream_t stream)
{
    const int*   x        = (const int*)  d_in[0];
    const float* emb      = (const float*)d_in[1];
    const float* fw0_wih  = (const float*)d_in[2];
    const float* fw0_bih  = (const float*)d_in[3];
    const float* fw0_whh  = (const float*)d_in[4];
    const float* fw0_bhh  = (const float*)d_in[5];
    const float* fw1_wih  = (const float*)d_in[6];
    const float* fw1_bih  = (const float*)d_in[7];
    const float* fw1_whh  = (const float*)d_in[8];
    const float* fw1_bhh  = (const float*)d_in[9];
    const float* bw0_wih  = (const float*)d_in[10];
    const float* bw0_bih  = (const float*)d_in[11];
    const float* bw0_whh  = (const float*)d_in[12];
    const float* bw0_bhh  = (const float*)d_in[13];
    const float* bw1_wih  = (const float*)d_in[14];
    const float* bw1_bih  = (const float*)d_in[15];
    const float* bw1_whh  = (const float*)d_in[16];
    const float* bw1_bhh  = (const float*)d_in[17];
    const float* fc1_w    = (const float*)d_in[18];
    const float* fc1_b    = (const float*)d_in[19];
    const float* fc2_w    = (const float*)d_in[20];
    const float* fc2_b    = (const float*)d_in[21];

    size_t off = 0;
    char* wsb = (char*)d_ws;
    auto take = [&](size_t bytes) -> void* {
        void* p = wsb + off;
        off += (bytes + 255) & ~(size_t)255;
        return p;
    };
    _Float16* W0f   = (_Float16*)take((size_t)HH * 1536 * 2);
    _Float16* W1f   = (_Float16*)take((size_t)HH * 2048 * 2);
    _Float16* W0b   = (_Float16*)take((size_t)HH * 1536 * 2);
    _Float16* W1b   = (_Float16*)take((size_t)HH * 2048 * 2);
    float*    bias  = (float*)   take(4096 * 4);
    u64*      h0f   = (u64*)     take((size_t)2 * 16384 * 8);
    u64*      h1f   = (u64*)     take((size_t)2 * 16384 * 8);
    u64*      h0b   = (u64*)     take((size_t)2 * 16384 * 8);
    u64*      h1b   = (u64*)     take((size_t)2 * 16384 * 8);
    float*    h1fin = (float*)   take((size_t)2 * BB * HH * 4);
    float*    vmid  = (float*)   take(4096 * 4);
    unsigned* ctr   = (unsigned*)take((size_t)4 * SS * 64 * 4);   // 4 chains x SS x 4 lines
    _Float16* embx  = (_Float16*)take((size_t)SS * BB * EE * 2);  // 32 MB
    bool use_embx = (ws_size >= off);

    prep_wt<<<1536, 256, 0, stream>>>(fw0_wih, fw0_whh, EE, 1536, W0f);
    prep_wt<<<2048, 256, 0, stream>>>(fw1_wih, fw1_whh, HH, 2048, W1f);
    prep_wt<<<1536, 256, 0, stream>>>(bw0_wih, bw0_whh, EE, 1536, W0b);
    prep_wt<<<2048, 256, 0, stream>>>(bw1_wih, bw1_whh, HH, 2048, W1b);
    prep_bias<<<1, 1024, 0, stream>>>(fw0_bih, fw0_bhh, fw1_bih, fw1_bhh,
                                      bw0_bih, bw0_bhh, bw1_bih, bw1_bhh, bias);
    if (use_embx)
        prep_embx<<<SS * BB, 128, 0, stream>>>(x, emb, embx);
    hipMemsetAsync(ctr, 0, (size_t)4 * SS * 64 * 4, stream);

    const _Float16* embx_arg = use_embx ? embx : nullptr;
    void* args[] = {(void*)&x, (void*)&emb, (void*)&embx_arg,
                    (void*)&W0f, (void*)&W1f, (void*)&W0b, (void*)&W1b,
                    (void*)&bias, (void*)&h0f, (void*)&h1f, (void*)&h0b, (void*)&h1b,
                    (void*)&h1fin, (void*)&ctr};
    hipLaunchCooperativeKernel((void*)rnn_persistent, dim3(256), dim3(256), args, 0, stream);

    fc1_kernel<<<16, 256, 0, stream>>>(h1fin, fc1_w, fc1_b, vmid);
    fc2_kernel<<<1, 128, 0, stream>>>(vmid, fc2_w, fc2_b, (float*)d_out);
}

// Round 5
// 4370.292 us; speedup vs baseline: 4.6197x; 1.2586x over previous
//
#include <hip/hip_runtime.h>
#include <hip/hip_bf16.h>
#include <hip/hip_fp16.h>

#define SS 512
#define BB 64
#define EE 512
#define HH 1024

typedef _Float16 f16x8 __attribute__((ext_vector_type(8)));
typedef _Float16 f16x4 __attribute__((ext_vector_type(4)));
typedef float f32x4 __attribute__((ext_vector_type(4)));
typedef unsigned long long u64;

__device__ __forceinline__ f16x8 ldh8(const _Float16* p) {
    return *reinterpret_cast<const f16x8*>(p);
}

// ---------- prep: [K1+K2][HH] fp32 (wih over whh) -> [HH][K] fp16, coalesced reads ----------
__global__ void prep_wt(const float* __restrict__ wih, const float* __restrict__ whh,
                        int K1, int K, _Float16* __restrict__ out)
{
    int k = blockIdx.x;                // source row (input feature)
    const float* src = (k < K1) ? (wih + (size_t)k * HH) : (whh + (size_t)(k - K1) * HH);
    for (int n = threadIdx.x; n < HH; n += blockDim.x)
        out[(size_t)n * K + k] = (_Float16)src[n];
}

// bias layout: [0]=L0 fwd, [1024]=L1 fwd, [2048]=L0 bwd, [3072]=L1 bwd (bih+bhh combined)
__global__ void prep_bias(const float* f0ih, const float* f0hh,
                          const float* f1ih, const float* f1hh,
                          const float* b0ih, const float* b0hh,
                          const float* b1ih, const float* b1hh,
                          float* __restrict__ bias)
{
    int i = threadIdx.x;
    bias[i]          = f0ih[i] + f0hh[i];
    bias[1024 + i]   = f1ih[i] + f1hh[i];
    bias[2048 + i]   = b0ih[i] + b0hh[i];
    bias[3072 + i]   = b1ih[i] + b1hh[i];
}

// ---------- embedding pre-gather: embx[t][b][e] = fp16(emb[x[b][t]][e]) ----------
__global__ void prep_embx(const int* __restrict__ x, const float* __restrict__ emb,
                          _Float16* __restrict__ embx)
{
    int t = blockIdx.x >> 6, b = blockIdx.x & 63;
    const float* src = emb + (size_t)x[b * SS + t] * EE;
    _Float16* dst = embx + ((size_t)t * BB + b) * EE;
    int i = threadIdx.x * 4;            // 128 threads * 4 = 512
    float4 v = *reinterpret_cast<const float4*>(src + i);
    f16x4 h;
    h[0] = (_Float16)v.x; h[1] = (_Float16)v.y;
    h[2] = (_Float16)v.z; h[3] = (_Float16)v.w;
    *reinterpret_cast<f16x4*>(dst + i) = h;
}

// ---------- fragment-tiled h state, accessed only via agent-scope (L3) ops ----------
// half-index(row,col) = (col>>5)*2048 + (row>>4)*512 + ((col>>3)&3)*128 + (row&15)*8 + (col&7)
// slot = 64x1024 halves = 16384 u64; 4 slots deep per buffer.
__device__ __forceinline__ f16x8 ld_tile(const u64* __restrict__ slot, int k0, int m, int kg, int r)
{
    union { u64 u[2]; f16x8 v; } z;
    const u64* p = slot + ((k0 >> 5) * 512 + m * 128 + kg * 32 + r * 2);
    z.u[0] = __hip_atomic_load(p,     __ATOMIC_RELAXED, __HIP_MEMORY_SCOPE_AGENT);
    z.u[1] = __hip_atomic_load(p + 1, __ATOMIC_RELAXED, __HIP_MEMORY_SCOPE_AGENT);
    return z.v;
}

__device__ __forceinline__ void st_tile(u64* __restrict__ slot, int row, int col4, f16x4 hv)
{
    union { u64 u; f16x4 v; } z; z.v = hv;
    u64* p = slot + ((col4 >> 5) * 512 + (row >> 4) * 128 + ((col4 >> 3) & 3) * 32
                     + (row & 15) * 2 + ((col4 >> 2) & 1));
    __hip_atomic_store(p, z.u, __ATOMIC_RELAXED, __HIP_MEMORY_SCOPE_AGENT);
}

// ---------- per-block monotonic flags, one 64B line each: flg[chain][block] ----------
// Per-wave wait: lane i checks slice-producer i (16 lines, a) and optional all-64 guard (b).
__device__ __forceinline__ void wave_wait(const unsigned* a /*16-line slice base*/, unsigned ta,
                                          const unsigned* b /*64-line base or null*/, unsigned tb)
{
    const int lane = threadIdx.x & 63;
    const unsigned* pa = a + (lane & 15) * 16;
    const unsigned* pb = b ? b + lane * 16 : nullptr;
    for (;;) {
        bool ok = __hip_atomic_load(pa, __ATOMIC_RELAXED, __HIP_MEMORY_SCOPE_AGENT) >= ta;
        if (pb)
            ok &= __hip_atomic_load(pb, __ATOMIC_RELAXED, __HIP_MEMORY_SCOPE_AGENT) >= tb;
        if (__all(ok)) break;
        __builtin_amdgcn_s_sleep(1);
    }
}

// ---------- persistent RNN kernel ----------
// 256 blocks: task = bid>>6 (0:L0f 1:L0b 2:L1f 3:L1b), tile = bid&63 -> 16 output cols.
// Weights in LDS; 4 waves split K; per-wave dataflow waits on per-block flags; h via L3.
__global__ __launch_bounds__(256, 1)
void rnn_persistent(const int* __restrict__ x, const float* __restrict__ emb,
                    const _Float16* __restrict__ embx,          // may be null -> gather in-loop
                    const _Float16* __restrict__ W0f, const _Float16* __restrict__ W1f,
                    const _Float16* __restrict__ W0b, const _Float16* __restrict__ W1b,
                    const float* __restrict__ bias,
                    u64* __restrict__ h0f, u64* __restrict__ h1f,
                    u64* __restrict__ h0b, u64* __restrict__ h1b,
                    float* __restrict__ h1fin, unsigned* __restrict__ flg)
{
    const int bid  = blockIdx.x;
    const int task = bid >> 6;
    const int tile = bid & 63;
    const int dir  = task & 1;
    const bool isL1 = task >= 2;
    const int lane = threadIdx.x & 63;
    const int wave = threadIdx.x >> 6;
    const int r    = lane & 15;       // output col within tile / A row within 16-frag
    const int kg   = lane >> 4;       // k-group (8 halves)
    const int tid  = threadIdx.x;

    const int K  = isL1 ? 2048 : 1536;
    const int Kp = K + 26;            // dword stride odd -> ds_read_b128 banks balanced

    __shared__ _Float16 Wlds[16 * 2074];      // 66,368 B
    __shared__ float red[4][64][20];          // 20,480 B

    // --- stage this block's weight slice into LDS (once) ---
    {
        const _Float16* Wg = isL1 ? (dir ? W1b : W1f) : (dir ? W0b : W0f);
        int rowlen = K >> 3;
        for (int idx = tid; idx < 16 * rowlen; idx += 256) {
            int row = idx / rowlen, kk = (idx - row * rowlen) * 8;
            f16x8 v = ldh8(Wg + (size_t)(tile * 16 + row) * K + kk);
            *reinterpret_cast<f16x8*>(&Wlds[row * Kp + kk]) = v;
        }
    }
    __syncthreads();

    u64* hbuf0 = dir ? h0b : h0f;     // layer0 state, 4 slots x 16384 u64
    u64* h1buf = dir ? h1b : h1f;

    unsigned* F_L0 = flg + (size_t)dir * 64 * 16;          // chains: 0,1 = L0 f/b
    unsigned* F_L1 = flg + (size_t)(2 + dir) * 64 * 16;    //         2,3 = L1 f/b
    unsigned* F_own = (isL1 ? F_L1 : F_L0) + tile * 16;
    const unsigned* myslice_L0 = F_L0 + 16 * wave * 16;    // wave's 16 slice producers
    const unsigned* myslice_L1 = F_L1 + 16 * wave * 16;

    for (int t = 0; t < SS; ++t) {
        f32x4 acc[4];
#pragma unroll
        for (int m = 0; m < 4; ++m) acc[m] = (f32x4){0.f, 0.f, 0.f, 0.f};

        if (!isL1) {
            // ===== layer 0, step t : A = [embx(t_eff) | h0(t-1)] =====
            const int t_eff = dir ? (SS - 1 - t) : t;
            // --- emb segment first (independent of recurrence): wave covers [wave*128,+128)
            if (embx) {
                const _Float16* Aemb = embx + (size_t)t_eff * (BB * EE);
#pragma unroll
                for (int i = 0; i < 4; ++i) {
                    const int k = wave * 128 + i * 32;
                    f16x8 bf = *reinterpret_cast<const f16x8*>(&Wlds[r * Kp + k + kg * 8]);
#pragma unroll
                    for (int m = 0; m < 4; ++m) {
                        f16x8 a = ldh8(Aemb + (m * 16 + r) * EE + k + kg * 8);
                        acc[m] = __builtin_amdgcn_mfma_f32_16x16x32_f16(a, bf, acc[m], 0, 0, 0);
                    }
                }
            } else {
                const float* erow[4];
#pragma unroll
                for (int m = 0; m < 4; ++m)
                    erow[m] = emb + (size_t)x[(m * 16 + r) * SS + t_eff] * EE;
#pragma unroll
                for (int i = 0; i < 4; ++i) {
                    const int k = wave * 128 + i * 32;
                    f16x8 bf = *reinterpret_cast<const f16x8*>(&Wlds[r * Kp + k + kg * 8]);
#pragma unroll
                    for (int m = 0; m < 4; ++m) {
                        const float* p = erow[m] + k + kg * 8;
                        float4 lo = *reinterpret_cast<const float4*>(p);
                        float4 hi = *reinterpret_cast<const float4*>(p + 4);
                        f16x8 a;
                        a[0] = (_Float16)lo.x; a[1] = (_Float16)lo.y;
                        a[2] = (_Float16)lo.z; a[3] = (_Float16)lo.w;
                        a[4] = (_Float16)hi.x; a[5] = (_Float16)hi.y;
                        a[6] = (_Float16)hi.z; a[7] = (_Float16)hi.w;
                        acc[m] = __builtin_amdgcn_mfma_f32_16x16x32_f16(a, bf, acc[m], 0, 0, 0);
                    }
                }
            }
            // --- wait: my k-slice of h0(t-1) ready (16 producers); slot guard vs L1(t-4)
            if (t >= 1) {
                wave_wait(myslice_L0, (unsigned)t,
                          (t >= 4) ? F_L1 : nullptr, (unsigned)(t - 3));
                const u64* hprev = hbuf0 + (size_t)((t - 1) & 3) * 16384;
#pragma unroll
                for (int i = 0; i < 8; ++i) {
                    const int k = wave * 256 + i * 32;
                    f16x8 bf = *reinterpret_cast<const f16x8*>(&Wlds[r * Kp + EE + k + kg * 8]);
#pragma unroll
                    for (int m = 0; m < 4; ++m) {
                        f16x8 a = ld_tile(hprev, k, m, kg, r);
                        acc[m] = __builtin_amdgcn_mfma_f32_16x16x32_f16(a, bf, acc[m], 0, 0, 0);
                    }
                }
            }
        } else {
            // ===== layer 1, step t : A = [h0(t) | h1(t-1)] =====
            // --- phase A: own-chain h1(t-1) first (usually ready earlier)
            if (t >= 1) {
                wave_wait(myslice_L1, (unsigned)t, nullptr, 0u);
                const u64* h1prev = h1buf + (size_t)((t - 1) & 3) * 16384;
#pragma unroll
                for (int i = 0; i < 8; ++i) {
                    const int k = wave * 256 + i * 32;
                    f16x8 bf = *reinterpret_cast<const f16x8*>(&Wlds[r * Kp + HH + k + kg * 8]);
#pragma unroll
                    for (int m = 0; m < 4; ++m) {
                        f16x8 a = ld_tile(h1prev, k, m, kg, r);
                        acc[m] = __builtin_amdgcn_mfma_f32_16x16x32_f16(a, bf, acc[m], 0, 0, 0);
                    }
                }
            }
            // --- phase B: h0(t) from L0 chain
            wave_wait(myslice_L0, (unsigned)(t + 1), nullptr, 0u);
            const u64* h0cur = hbuf0 + (size_t)(t & 3) * 16384;
#pragma unroll
            for (int i = 0; i < 8; ++i) {
                const int k = wave * 256 + i * 32;
                f16x8 bf = *reinterpret_cast<const f16x8*>(&Wlds[r * Kp + k + kg * 8]);
#pragma unroll
                for (int m = 0; m < 4; ++m) {
                    f16x8 a = ld_tile(h0cur, k, m, kg, r);
                    acc[m] = __builtin_amdgcn_mfma_f32_16x16x32_f16(a, bf, acc[m], 0, 0, 0);
                }
            }
        }

        // ---------- cross-wave reduce + epilogue ----------
#pragma unroll
        for (int m = 0; m < 4; ++m)
#pragma unroll
            for (int rr = 0; rr < 4; ++rr)
                red[wave][m * 16 + kg * 4 + rr][r] = acc[m][rr];
        __syncthreads();
        {
            const int row = tid >> 2;          // 0..63
            const int c   = (tid & 3) * 4;     // 0,4,8,12
            f32x4 s = *reinterpret_cast<f32x4*>(&red[0][row][c]);
#pragma unroll
            for (int w = 1; w < 4; ++w) s += *reinterpret_cast<f32x4*>(&red[w][row][c]);
            const int nb = tile * 16 + c;
            const float* bp = bias + (isL1 ? 1024 : 0) + (dir ? 2048 : 0) + nb;
            float4 bv = *reinterpret_cast<const float4*>(bp);
            float v0 = tanhf(s[0] + bv.x), v1 = tanhf(s[1] + bv.y);
            float v2 = tanhf(s[2] + bv.z), v3 = tanhf(s[3] + bv.w);
            f16x4 hv; hv[0] = (_Float16)v0; hv[1] = (_Float16)v1;
            hv[2] = (_Float16)v2; hv[3] = (_Float16)v3;
            u64* hout = (isL1 ? h1buf : hbuf0) + (size_t)(t & 3) * 16384;
            st_tile(hout, row, nb, hv);
            if (isL1 && t == SS - 1) {
                float4 fv; fv.x = v0; fv.y = v1; fv.z = v2; fv.w = v3;
                *reinterpret_cast<float4*>(h1fin + (size_t)dir * (BB * HH) + row * HH + nb) = fv;
            }
        }
        // ---------- publish: drain all waves' sc1 stores, then flag = t+1 (plain store)
        __syncthreads();
        if (tid == 0)
            __hip_atomic_store(F_own, (unsigned)(t + 1), __ATOMIC_RELAXED,
                               __HIP_MEMORY_SCOPE_AGENT);
    }
}

// ---------- FC head (all fp32, runs once) ----------
__global__ void fc1_kernel(const float* __restrict__ h1fin, const float* __restrict__ w,
                           const float* __restrict__ b, float* __restrict__ v)
{
    int idx = blockIdx.x * 256 + threadIdx.x;   // (batch, out-feature)
    int bb = idx >> 6, nn = idx & 63;
    const float* hf = h1fin + bb * HH;
    const float* hb = h1fin + BB * HH + bb * HH;
    float s = b[nn];
#pragma unroll 8
    for (int k = 0; k < HH; ++k) s += hf[k] * w[k * 64 + nn];
#pragma unroll 8
    for (int k = 0; k < HH; ++k) s += hb[k] * w[(HH + k) * 64 + nn];
    v[idx] = s;
}

__global__ void fc2_kernel(const float* __restrict__ v, const float* __restrict__ w,
                           const float* __restrict__ b, float* __restrict__ out)
{
    int idx = threadIdx.x;
    if (idx >= BB * 2) return;
    int bb = idx >> 1, c = idx & 1;
    float s = b[c];
    const float* vb = v + bb * 64;
#pragma unroll
    for (int j = 0; j < 64; ++j) s += vb[j] * w[j * 2 + c];
    out[bb * 2 + c] = s;
}

extern "C" void kernel_launch(void* const* d_in, const int* in_sizes, int n_in,
                              void* d_out, int out_size, void* d_ws, size_t ws_size,
                              hipStream_t stream)
{
    const int*   x        = (const int*)  d_in[0];
    const float* emb      = (const float*)d_in[1];
    const float* fw0_wih  = (const float*)d_in[2];
    const float* fw0_bih  = (const float*)d_in[3];
    const float* fw0_whh  = (const float*)d_in[4];
    const float* fw0_bhh  = (const float*)d_in[5];
    const float* fw1_wih  = (const float*)d_in[6];
    const float* fw1_bih  = (const float*)d_in[7];
    const float* fw1_whh  = (const float*)d_in[8];
    const float* fw1_bhh  = (const float*)d_in[9];
    const float* bw0_wih  = (const float*)d_in[10];
    const float* bw0_bih  = (const float*)d_in[11];
    const float* bw0_whh  = (const float*)d_in[12];
    const float* bw0_bhh  = (const float*)d_in[13];
    const float* bw1_wih  = (const float*)d_in[14];
    const float* bw1_bih  = (const float*)d_in[15];
    const float* bw1_whh  = (const float*)d_in[16];
    const float* bw1_bhh  = (const float*)d_in[17];
    const float* fc1_w    = (const float*)d_in[18];
    const float* fc1_b    = (const float*)d_in[19];
    const float* fc2_w    = (const float*)d_in[20];
    const float* fc2_b    = (const float*)d_in[21];

    size_t off = 0;
    char* wsb = (char*)d_ws;
    auto take = [&](size_t bytes) -> void* {
        void* p = wsb + off;
        off += (bytes + 255) & ~(size_t)255;
        return p;
    };
    _Float16* W0f   = (_Float16*)take((size_t)HH * 1536 * 2);
    _Float16* W1f   = (_Float16*)take((size_t)HH * 2048 * 2);
    _Float16* W0b   = (_Float16*)take((size_t)HH * 1536 * 2);
    _Float16* W1b   = (_Float16*)take((size_t)HH * 2048 * 2);
    float*    bias  = (float*)   take(4096 * 4);
    u64*      h0f   = (u64*)     take((size_t)4 * 16384 * 8);
    u64*      h1f   = (u64*)     take((size_t)4 * 16384 * 8);
    u64*      h0b   = (u64*)     take((size_t)4 * 16384 * 8);
    u64*      h1b   = (u64*)     take((size_t)4 * 16384 * 8);
    float*    h1fin = (float*)   take((size_t)2 * BB * HH * 4);
    float*    vmid  = (float*)   take(4096 * 4);
    unsigned* flg   = (unsigned*)take((size_t)4 * 64 * 16 * 4);   // 4 chains x 64 blocks x 64B
    _Float16* embx  = (_Float16*)take((size_t)SS * BB * EE * 2);  // 32 MB
    bool use_embx = (ws_size >= off);

    prep_wt<<<1536, 256, 0, stream>>>(fw0_wih, fw0_whh, EE, 1536, W0f);
    prep_wt<<<2048, 256, 0, stream>>>(fw1_wih, fw1_whh, HH, 2048, W1f);
    prep_wt<<<1536, 256, 0, stream>>>(bw0_wih, bw0_whh, EE, 1536, W0b);
    prep_wt<<<2048, 256, 0, stream>>>(bw1_wih, bw1_whh, HH, 2048, W1b);
    prep_bias<<<1, 1024, 0, stream>>>(fw0_bih, fw0_bhh, fw1_bih, fw1_bhh,
                                      bw0_bih, bw0_bhh, bw1_bih, bw1_bhh, bias);
    if (use_embx)
        prep_embx<<<SS * BB, 128, 0, stream>>>(x, emb, embx);
    hipMemsetAsync(flg, 0, (size_t)4 * 64 * 16 * 4, stream);

    const _Float16* embx_arg = use_embx ? embx : nullptr;
    void* args[] = {(void*)&x, (void*)&emb, (void*)&embx_arg,
                    (void*)&W0f, (void*)&W1f, (void*)&W0b, (void*)&W1b,
                    (void*)&bias, (void*)&h0f, (void*)&h1f, (void*)&h0b, (void*)&h1b,
                    (void*)&h1fin, (void*)&flg};
    hipLaunchCooperativeKernel((void*)rnn_persistent, dim3(256), dim3(256), args, 0, stream);

    fc1_kernel<<<16, 256, 0, stream>>>(h1fin, fc1_w, fc1_b, vmid);
    fc2_kernel<<<1, 128, 0, stream>>>(vmid, fc2_w, fc2_b, (float*)d_out);
}